// Round 14
// baseline (209.540 us; speedup 1.0000x reference)
//
#include <hip/hip_runtime.h>
#include <cstdint>

// BinConv2dEval: y = conv3x3(x,W) + bias; out = (sign*y >= 0) ? 1 : 0
// x: [32][128][64][64] fp32 in {0,1};  W: [256][128][3][3] fp32 in {-1,0,1}
// bias: [256] integer-valued fp32; sign: [256] in {-1,+1}; out fp32 NCHW.
//
// R11-R13 (kept, verified): fused MX-FP4 GEMM — per-block LDS build of the
// swizzled fp4 X-strip (Phase A pair-pack, Phase B transpose),
// mfma_scale_f32_32x32x64_f8f6f4 (exact), direct NT epilogue.
// R14: HALO AMORTIZATION. 4 output rows per block (6 staged rows, 1.5x
// halo vs 2.0x): 1024 thr = 16 waves, wave = (co-quarter, row) keeping the
// verified 64co x 64m shape. Full occupancy preserved (2 blk/CU x 16 =
// 32 waves/CU; LDS 50.25 KB). Phase A/B work and x re-fetch drop 25%.
//  ws: wq4 = fp4 fragment-major [tap(9)][co32(8)][s(2)][lane(64)x16B] (144 KB)

#define NIMG 32
#define CIN  128
#define HH   64
#define WW   64
#define COUT 256
#define NROW 4                        // output rows per block
#define NSTG 6                        // staged padded rows
#define X4ROW   4224                  // 66 px * 64 B
#define STG_SY  4352                  // 64 cipair * 68 B
#define STG_BYTES (NSTG * STG_SY)     // 26112
#define LDS_TOTAL (STG_BYTES + NSTG * X4ROW)   // 51456
#define WQ4_BYTES ((size_t)9 * 8 * 2 * 64 * 16)   // 147456

typedef int   v4i  __attribute__((ext_vector_type(4)));
typedef int   v8i  __attribute__((ext_vector_type(8)));
typedef float v16f __attribute__((ext_vector_type(16)));

// -------------------------------------------------------------------------
// Weight prepack: OIHW fp32 -> fp4 fragment-major wq4 (verified R11-R13).
// byte b of a fragment = ci pair (2b even -> low nibble, 2b+1 -> high).
__global__ __launch_bounds__(256) void w_prepack(const float* __restrict__ w,
                                                 int8_t* __restrict__ wq4) {
    const int idx = blockIdx.x * 256 + threadIdx.x;   // 0..147455
    if (idx >= (int)WQ4_BYTES) return;
    const int b    = idx & 15;
    const int lane = (idx >> 4) & 63;
    const int s    = (idx >> 10) & 1;
    const int co32 = (idx >> 11) & 7;
    const int tap  = idx >> 14;             // 0..8
    const int co   = co32 * 32 + (lane & 31);
    const int ci0  = s * 64 + (lane >> 5) * 32 + b * 2;
    const int i0 = (int)w[(size_t)(co * CIN + ci0) * 9 + tap];
    const int i1 = (int)w[(size_t)(co * CIN + ci0 + 1) * 9 + tap];
    const uint32_t n0 = (i0 == 0) ? 0u : ((i0 > 0) ? 0x2u : 0xAu);
    const uint32_t n1 = (i1 == 0) ? 0u : ((i1 > 0) ? 0x2u : 0xAu);
    wq4[idx] = (int8_t)(n0 | (n1 << 4));
}

__device__ __forceinline__ v8i widen(v4i x) {
    v8i r = {x[0], x[1], x[2], x[3], 0, 0, 0, 0};   // fp4 uses low 4 regs
    return r;
}

// -------------------------------------------------------------------------
// Fused kernel. grid 512 = n(32) x ystrip(16); block 1024 = 16 waves.
__global__ __launch_bounds__(1024) void binconv_fused(
    const float* __restrict__ x, const int8_t* __restrict__ wq4,
    const float* __restrict__ bias, const float* __restrict__ sign,
    float* __restrict__ out) {

    __shared__ __align__(16) int8_t Smem[LDS_TOTAL];
    int8_t* Stg = Smem;                 // [6 sy][64 cipair][68] nibble-pair bytes
    int8_t* X4  = Smem + STG_BYTES;     // [6 sy][66 px][64 B] fp4 swizzled

    const int t  = threadIdx.x;
    const int bx = blockIdx.x;
    const int n  = bx >> 4;
    const int y0 = (bx & 15) << 2;      // 4 output rows per block

    // ---- Phase A: x -> nibble-pair bytes in staging (384 threads) ----
    if (t < 64 * NSTG) {
        const int sy = t >> 6;          // strip row 0..5
        const int pr = t & 63;          // ci pair
        const int y  = y0 + sy - 1;
        uint32_t* sp = (uint32_t*)(Stg + sy * STG_SY + pr * 68);
        if (y >= 0 && y < HH) {
            const uint4* r0 =
                (const uint4*)(x + (((size_t)n * CIN + 2 * pr)     * HH + y) * WW);
            const uint4* r1 =
                (const uint4*)(x + (((size_t)n * CIN + 2 * pr + 1) * HH + y) * WW);
#pragma unroll
            for (int q = 0; q < 16; ++q) {
                const uint4 a = r0[q], b = r1[q];
                // byte i = fp4(even ci) | fp4(odd ci)<<4 ; 1.0f has bit pattern
                // 0x3f800000 (bits 28,29 set) -> (>>28)&2 = 0x2 nibble
                uint32_t wd = ((a.x >> 28) & 0x2u)        | ((b.x >> 24) & 0x20u)
                            | ((a.y >> 20) & 0x200u)      | ((b.y >> 16) & 0x2000u)
                            | ((a.z >> 12) & 0x20000u)    | ((b.z >> 8) & 0x200000u)
                            | ((a.w >> 4)  & 0x2000000u)  | ( b.w       & 0x20000000u);
                sp[q] = wd;
            }
        } else {
#pragma unroll
            for (int q = 0; q < 16; ++q) sp[q] = 0u;
        }
    }
    __syncthreads();

    // ---- Phase B: transpose -> swizzled fp4 pixel blocks (396 threads) ----
    if (t < 66 * NSTG) {
        const int sy  = t / 66;
        const int pxp = t - sy * 66;    // padded pixel 0..65
        int8_t* dst = X4 + sy * X4ROW + pxp * 64;
        if (pxp == 0 || pxp == 65) {
            const int4 z = {0, 0, 0, 0};
#pragma unroll
            for (int c = 0; c < 4; ++c) *(int4*)(dst + c * 16) = z;
        } else {
            const int8_t* src = Stg + sy * STG_SY + (pxp - 1);
            uint32_t wrd[16];
#pragma unroll
            for (int k = 0; k < 16; ++k) {
                const uint32_t b0 = (uint8_t)src[(4 * k + 0) * 68];
                const uint32_t b1 = (uint8_t)src[(4 * k + 1) * 68];
                const uint32_t b2 = (uint8_t)src[(4 * k + 2) * 68];
                const uint32_t b3 = (uint8_t)src[(4 * k + 3) * 68];
                wrd[k] = b0 | (b1 << 8) | (b2 << 16) | (b3 << 24);
            }
            const int sk = pxp & 3;     // chunk swizzle key (verified pattern)
#pragma unroll
            for (int c = 0; c < 4; ++c) {
                int4 vv = {(int)wrd[c*4], (int)wrd[c*4+1],
                           (int)wrd[c*4+2], (int)wrd[c*4+3]};
                *(int4*)(dst + ((c ^ sk) << 4)) = vv;
            }
        }
    }
    __syncthreads();

    // ---- Phase C: GEMM (verified structure; wave = (co-quarter, row)) ----
    const int wid  = t >> 6;            // 0..15
    const int lane = t & 63;
    const int m_lo = lane & 31;         // D col (m); A co row
    const int hi   = lane >> 5;         // k-half
    const int co_off = (wid >> 2) * 64; // 0,64,128,192
    const int yw     = wid & 3;         // output row y0+yw
    const int ct0    = co_off >> 5;     // first co32 tile

    const int8_t* Xw  = X4 + yw * X4ROW;
    const int8_t* wqb = wq4 + lane * 16;

    v16f acc[2][2] = {};                // [ct][mt], fp32 exact

#pragma unroll
    for (int tap = 0; tap < 9; ++tap) {
        const int ky = tap / 3, kx = tap % 3;
        const int8_t* xl = Xw + ky * X4ROW;
        const int px0 = m_lo + kx;
        const int pk  = px0 & 3;

        v4i af[2][2];                   // [ct][s]
#pragma unroll
        for (int c = 0; c < 2; ++c)
#pragma unroll
            for (int s = 0; s < 2; ++s)
                af[c][s] = *(const v4i*)(wqb
                    + ((((tap * 8 + ct0 + c) * 2) + s) << 10));

        v4i bf[2][2];                   // [mt][s]
#pragma unroll
        for (int s = 0; s < 2; ++s) {
            const int sw = (((s << 1) + hi) ^ pk) << 4;
#pragma unroll
            for (int m = 0; m < 2; ++m)
                bf[m][s] = *(const v4i*)(xl + (px0 + m * 32) * 64 + sw);
        }
#pragma unroll
        for (int s = 0; s < 2; ++s)
#pragma unroll
            for (int c = 0; c < 2; ++c)
#pragma unroll
                for (int m = 0; m < 2; ++m)
                    acc[c][m] = __builtin_amdgcn_mfma_scale_f32_32x32x64_f8f6f4(
                        widen(af[c][s]), widen(bf[m][s]), acc[c][m],
                        4, 4,             // cbsz=fp4, blgp=fp4
                        0, 0x7F7F7F7F,    // scale_a = 2^0
                        0, 0x7F7F7F7F);   // scale_b = 2^0
    }

    // ---- epilogue: direct NT dword stores from acc.
    // D 32x32 layout: col(m) = lane&31, row(co) = (r&3)+8*(r>>2)+4*hi.
    const float* bco = bias + co_off;
    const float* sco = sign + co_off;
    float* outb = out + ((size_t)n * COUT + co_off) * (HH * WW)
                + (y0 + yw) * WW + m_lo;
#pragma unroll
    for (int c = 0; c < 2; ++c) {
#pragma unroll
        for (int r = 0; r < 16; ++r) {
            const int co_l = c * 32 + (r & 3) + 8 * (r >> 2) + 4 * hi;
            const float bv = bco[co_l];
            const float sv = sco[co_l];
            float* orow = outb + (size_t)co_l * (HH * WW);
#pragma unroll
            for (int m = 0; m < 2; ++m) {
                const float yv = acc[c][m][r] + bv;     // exact integer
                const bool on = (sv > 0.0f) ? (yv >= 0.0f) : (yv <= 0.0f);
                __builtin_nontemporal_store(on ? 1.0f : 0.0f, orow + m * 32);
            }
        }
    }
}

// -------------------------------------------------------------------------
// Fallback (only if ws too small): naive direct conv.
__global__ __launch_bounds__(256) void naive_conv(
    const float* __restrict__ x, const float* __restrict__ w,
    const float* __restrict__ bias, const float* __restrict__ sign,
    float* __restrict__ out) {
    const int idx = blockIdx.x * 256 + threadIdx.x;
    const int xc = idx & 63, y = (idx >> 6) & 63, co = (idx >> 12) & 255,
              n = idx >> 20;
    float s = 0.f;
    for (int ci = 0; ci < CIN; ++ci)
        for (int ky = 0; ky < 3; ++ky) {
            const int iy = y + ky - 1;
            if (iy < 0 || iy >= HH) continue;
            for (int kx = 0; kx < 3; ++kx) {
                const int ix = xc + kx - 1;
                if (ix < 0 || ix >= WW) continue;
                s += x[((size_t)(n * CIN + ci) * HH + iy) * WW + ix] *
                     w[((size_t)(co * CIN + ci) * 3 + ky) * 3 + kx];
            }
        }
    const float yv = s + bias[co];
    out[idx] = ((sign[co] > 0.f) ? (yv >= 0.f) : (yv <= 0.f)) ? 1.0f : 0.0f;
}

// -------------------------------------------------------------------------
extern "C" void kernel_launch(void* const* d_in, const int* in_sizes, int n_in,
                              void* d_out, int out_size, void* d_ws, size_t ws_size,
                              hipStream_t stream) {
    const float* x    = (const float*)d_in[0];
    const float* w    = (const float*)d_in[1];
    const float* bias = (const float*)d_in[2];
    const float* sign = (const float*)d_in[3];
    float* out = (float*)d_out;

    if (ws_size < WQ4_BYTES) {
        naive_conv<<<dim3((NIMG * COUT * HH * WW) / 256), 256, 0, stream>>>(
            x, w, bias, sign, out);
        return;
    }
    int8_t* wq4 = (int8_t*)d_ws;

    w_prepack<<<dim3((int)((WQ4_BYTES + 255) / 256)), 256, 0, stream>>>(w, wq4);
    binconv_fused<<<dim3(NIMG * (HH / NROW)), 1024, 0, stream>>>(
        x, wq4, bias, sign, out);
}

// Round 15
// 205.279 us; speedup vs baseline: 1.0208x; 1.0208x over previous
//
#include <hip/hip_runtime.h>
#include <cstdint>

// BinConv2dEval: y = conv3x3(x,W) + bias; out = (sign*y >= 0) ? 1 : 0
// x: [32][128][64][64] fp32 in {0,1};  W: [256][128][3][3] fp32 in {-1,0,1}
// bias: [256] integer-valued fp32; sign: [256] in {-1,+1}; out fp32 NCHW.
//
// FINAL = R13 (best measured: 206.2 us total; fused kernel ~58 us).
// R11: MX-FP4 GEMM via mfma_scale_f32_32x32x64_f8f6f4 (exact fp32 accum),
//      chunk-swizzled pixel blocks (0 LDS bank conflicts, verified).
// R12: fused per-block LDS build of the fp4 X-strip (no prepass kernel,
//      no xt round-trip). R13: pair-packed Phase A + direct NT epilogue.
// R14 (1024-thr, 4-row strips) regressed -> reverted.
//  ws: wq4 = fp4 fragment-major [tap(9)][co32(8)][s(2)][lane(64)x16B] (144 KB)

#define NIMG 32
#define CIN  128
#define HH   64
#define WW   64
#define COUT 256
#define X4ROW   4224                  // 66 px * 64 B
#define STG_SY  4352                  // 64 cipair * 68 B
#define STG_BYTES (4 * STG_SY)        // 17408
#define LDS_TOTAL (STG_BYTES + 4 * X4ROW)   // 34304
#define WQ4_BYTES ((size_t)9 * 8 * 2 * 64 * 16)   // 147456

typedef int   v4i  __attribute__((ext_vector_type(4)));
typedef int   v8i  __attribute__((ext_vector_type(8)));
typedef float v16f __attribute__((ext_vector_type(16)));

// -------------------------------------------------------------------------
// Weight prepack: OIHW fp32 -> fp4 fragment-major wq4 (verified R11-R13).
// byte b of a fragment = ci pair (2b even -> low nibble, 2b+1 -> high).
__global__ __launch_bounds__(256) void w_prepack(const float* __restrict__ w,
                                                 int8_t* __restrict__ wq4) {
    const int idx = blockIdx.x * 256 + threadIdx.x;   // 0..147455
    if (idx >= (int)WQ4_BYTES) return;
    const int b    = idx & 15;
    const int lane = (idx >> 4) & 63;
    const int s    = (idx >> 10) & 1;
    const int co32 = (idx >> 11) & 7;
    const int tap  = idx >> 14;             // 0..8
    const int co   = co32 * 32 + (lane & 31);
    const int ci0  = s * 64 + (lane >> 5) * 32 + b * 2;
    const int i0 = (int)w[(size_t)(co * CIN + ci0) * 9 + tap];
    const int i1 = (int)w[(size_t)(co * CIN + ci0 + 1) * 9 + tap];
    const uint32_t n0 = (i0 == 0) ? 0u : ((i0 > 0) ? 0x2u : 0xAu);
    const uint32_t n1 = (i1 == 0) ? 0u : ((i1 > 0) ? 0x2u : 0xAu);
    wq4[idx] = (int8_t)(n0 | (n1 << 4));
}

__device__ __forceinline__ v8i widen(v4i x) {
    v8i r = {x[0], x[1], x[2], x[3], 0, 0, 0, 0};   // fp4 uses low 4 regs
    return r;
}

// -------------------------------------------------------------------------
// Fused kernel. grid 1024 = n(32) x ystrip(32); block 512 = 8 waves.
__global__ __launch_bounds__(512) void binconv_fused(
    const float* __restrict__ x, const int8_t* __restrict__ wq4,
    const float* __restrict__ bias, const float* __restrict__ sign,
    float* __restrict__ out) {

    __shared__ __align__(16) int8_t Smem[LDS_TOTAL];
    int8_t* Stg = Smem;                 // [4 sy][64 cipair][68] nibble-pair bytes
    int8_t* X4  = Smem + STG_BYTES;     // [4 sy][66 px][64 B] fp4 swizzled

    const int t  = threadIdx.x;
    const int bx = blockIdx.x;
    const int n  = bx >> 5;
    const int y0 = (bx & 31) << 1;      // 2 output rows per block

    // ---- Phase A: x -> nibble-pair bytes in staging (256 threads) ----
    if (t < 256) {
        const int sy = t >> 6;          // strip row 0..3
        const int pr = t & 63;          // ci pair
        const int y  = y0 + sy - 1;
        uint32_t* sp = (uint32_t*)(Stg + sy * STG_SY + pr * 68);
        if (y >= 0 && y < HH) {
            const uint4* r0 =
                (const uint4*)(x + (((size_t)n * CIN + 2 * pr)     * HH + y) * WW);
            const uint4* r1 =
                (const uint4*)(x + (((size_t)n * CIN + 2 * pr + 1) * HH + y) * WW);
#pragma unroll
            for (int q = 0; q < 16; ++q) {
                const uint4 a = r0[q], b = r1[q];
                // byte i = fp4(even ci) | fp4(odd ci)<<4 ; 1.0f has bits 28,29 set
                uint32_t wd = ((a.x >> 28) & 0x2u)        | ((b.x >> 24) & 0x20u)
                            | ((a.y >> 20) & 0x200u)      | ((b.y >> 16) & 0x2000u)
                            | ((a.z >> 12) & 0x20000u)    | ((b.z >> 8) & 0x200000u)
                            | ((a.w >> 4)  & 0x2000000u)  | ( b.w       & 0x20000000u);
                sp[q] = wd;
            }
        } else {
#pragma unroll
            for (int q = 0; q < 16; ++q) sp[q] = 0u;
        }
    }
    __syncthreads();

    // ---- Phase B: transpose -> swizzled fp4 pixel blocks (264 threads) ----
    if (t < 264) {
        const int sy  = t / 66;
        const int pxp = t - sy * 66;    // padded pixel 0..65
        int8_t* dst = X4 + sy * X4ROW + pxp * 64;
        if (pxp == 0 || pxp == 65) {
            const int4 z = {0, 0, 0, 0};
#pragma unroll
            for (int c = 0; c < 4; ++c) *(int4*)(dst + c * 16) = z;
        } else {
            const int8_t* src = Stg + sy * STG_SY + (pxp - 1);
            uint32_t wrd[16];
#pragma unroll
            for (int k = 0; k < 16; ++k) {
                const uint32_t b0 = (uint8_t)src[(4 * k + 0) * 68];
                const uint32_t b1 = (uint8_t)src[(4 * k + 1) * 68];
                const uint32_t b2 = (uint8_t)src[(4 * k + 2) * 68];
                const uint32_t b3 = (uint8_t)src[(4 * k + 3) * 68];
                wrd[k] = b0 | (b1 << 8) | (b2 << 16) | (b3 << 24);
            }
            const int sk = pxp & 3;     // chunk swizzle key (verified pattern)
#pragma unroll
            for (int c = 0; c < 4; ++c) {
                int4 vv = {(int)wrd[c*4], (int)wrd[c*4+1],
                           (int)wrd[c*4+2], (int)wrd[c*4+3]};
                *(int4*)(dst + ((c ^ sk) << 4)) = vv;
            }
        }
    }
    __syncthreads();

    // ---- Phase C: GEMM (verified R11/R12 structure) ----
    const int wid  = t >> 6;            // 0..7
    const int lane = t & 63;
    const int m_lo = lane & 31;         // D col (m); A co row
    const int hi   = lane >> 5;         // k-half
    const int co_off = (wid >> 1) * 64; // 0,64,128,192
    const int yw     = wid & 1;         // output row y0 / y0+1
    const int ct0    = co_off >> 5;     // first co32 tile

    const int8_t* Xw  = X4 + yw * X4ROW;
    const int8_t* wqb = wq4 + lane * 16;

    v16f acc[2][2] = {};                // [ct][mt], fp32 exact

#pragma unroll
    for (int tap = 0; tap < 9; ++tap) {
        const int ky = tap / 3, kx = tap % 3;
        const int8_t* xl = Xw + ky * X4ROW;
        const int px0 = m_lo + kx;
        const int pk  = px0 & 3;

        v4i af[2][2];                   // [ct][s]
#pragma unroll
        for (int c = 0; c < 2; ++c)
#pragma unroll
            for (int s = 0; s < 2; ++s)
                af[c][s] = *(const v4i*)(wqb
                    + ((((tap * 8 + ct0 + c) * 2) + s) << 10));

        v4i bf[2][2];                   // [mt][s]
#pragma unroll
        for (int s = 0; s < 2; ++s) {
            const int sw = (((s << 1) + hi) ^ pk) << 4;
#pragma unroll
            for (int m = 0; m < 2; ++m)
                bf[m][s] = *(const v4i*)(xl + (px0 + m * 32) * 64 + sw);
        }
#pragma unroll
        for (int s = 0; s < 2; ++s)
#pragma unroll
            for (int c = 0; c < 2; ++c)
#pragma unroll
                for (int m = 0; m < 2; ++m)
                    acc[c][m] = __builtin_amdgcn_mfma_scale_f32_32x32x64_f8f6f4(
                        widen(af[c][s]), widen(bf[m][s]), acc[c][m],
                        4, 4,             // cbsz=fp4, blgp=fp4
                        0, 0x7F7F7F7F,    // scale_a = 2^0
                        0, 0x7F7F7F7F);   // scale_b = 2^0
    }

    // ---- epilogue: direct NT dword stores from acc (no LDS round-trip).
    // D 32x32 layout: col(m) = lane&31, row(co) = (r&3)+8*(r>>2)+4*hi.
    const float* bco = bias + co_off;
    const float* sco = sign + co_off;
    float* outb = out + ((size_t)n * COUT + co_off) * (HH * WW)
                + (y0 + yw) * WW + m_lo;
#pragma unroll
    for (int c = 0; c < 2; ++c) {
#pragma unroll
        for (int r = 0; r < 16; ++r) {
            const int co_l = c * 32 + (r & 3) + 8 * (r >> 2) + 4 * hi;
            const float bv = bco[co_l];
            const float sv = sco[co_l];
            float* orow = outb + (size_t)co_l * (HH * WW);
#pragma unroll
            for (int m = 0; m < 2; ++m) {
                const float yv = acc[c][m][r] + bv;     // exact integer
                const bool on = (sv > 0.0f) ? (yv >= 0.0f) : (yv <= 0.0f);
                __builtin_nontemporal_store(on ? 1.0f : 0.0f, orow + m * 32);
            }
        }
    }
}

// -------------------------------------------------------------------------
// Fallback (only if ws too small): naive direct conv.
__global__ __launch_bounds__(256) void naive_conv(
    const float* __restrict__ x, const float* __restrict__ w,
    const float* __restrict__ bias, const float* __restrict__ sign,
    float* __restrict__ out) {
    const int idx = blockIdx.x * 256 + threadIdx.x;
    const int xc = idx & 63, y = (idx >> 6) & 63, co = (idx >> 12) & 255,
              n = idx >> 20;
    float s = 0.f;
    for (int ci = 0; ci < CIN; ++ci)
        for (int ky = 0; ky < 3; ++ky) {
            const int iy = y + ky - 1;
            if (iy < 0 || iy >= HH) continue;
            for (int kx = 0; kx < 3; ++kx) {
                const int ix = xc + kx - 1;
                if (ix < 0 || ix >= WW) continue;
                s += x[((size_t)(n * CIN + ci) * HH + iy) * WW + ix] *
                     w[((size_t)(co * CIN + ci) * 3 + ky) * 3 + kx];
            }
        }
    const float yv = s + bias[co];
    out[idx] = ((sign[co] > 0.f) ? (yv >= 0.f) : (yv <= 0.f)) ? 1.0f : 0.0f;
}

// -------------------------------------------------------------------------
extern "C" void kernel_launch(void* const* d_in, const int* in_sizes, int n_in,
                              void* d_out, int out_size, void* d_ws, size_t ws_size,
                              hipStream_t stream) {
    const float* x    = (const float*)d_in[0];
    const float* w    = (const float*)d_in[1];
    const float* bias = (const float*)d_in[2];
    const float* sign = (const float*)d_in[3];
    float* out = (float*)d_out;

    if (ws_size < WQ4_BYTES) {
        naive_conv<<<dim3((NIMG * COUT * HH * WW) / 256), 256, 0, stream>>>(
            x, w, bias, sign, out);
        return;
    }
    int8_t* wq4 = (int8_t*)d_ws;

    w_prepack<<<dim3((int)((WQ4_BYTES + 255) / 256)), 256, 0, stream>>>(w, wq4);
    binconv_fused<<<dim3(NIMG * (HH / 2)), 512, 0, stream>>>(
        x, wq4, bias, sign, out);
}